// Round 5
// baseline (2428.208 us; speedup 1.0000x reference)
//
#include <hip/hip_runtime.h>
#include <cmath>

// ConvLSTM round 12: persistent kernel, critical-path restructure.
// Round-11 post-mortem: FETCH stayed 2.35 GB (= full request stream, ~zero L2
// hits) because b-pinning put same-weight blocks on DIFFERENT XCDs and the
// per-XCD x/h stream still turned the 4 MB L2 over each step. 90 us/step vs
// 7.7 us MFMA floor = latency chain, not bandwidth.
// Fixes:
//  1) q pinned per XCD-pair (q=(bid&7)>>1): all blocks on an XCD share ONE
//     144 KB weight quarter -> weights L2-resident. Locality-only.
//  2) x-conv(t+1) computed during step t into a carried 2nd accumulator bank;
//     step t+1 starts from it. Critical path/step = h-stage -> 288 MFMA ->
//     gates -> arrive. x-stage/Wx/288 MFMA run between arrive and wait
//     (barrier slack). Bit-identical math (same fragment order per gate).
//  3) barrier split: arrive right after h stores drain; wait after x-work.
// Proven-safe envelope kept: 512 blocks, 256 thr, LDS 51.8 KB, lb(256,2).

#define CHW 262144             // 64*64*64
#define ZSZ 12960              // ushorts per z buffer (324*40)
#define BBLK 64u               // blocks per batch (16 tiles x 4 quarters)

typedef short bf16x8 __attribute__((ext_vector_type(8)));
typedef float f32x4  __attribute__((ext_vector_type(4)));

static __device__ __forceinline__ ushort f2bf(float f) {
    union { float f; unsigned u; } v; v.f = f;
    unsigned u = v.u;
    return (ushort)((u + 0x7FFFu + ((u >> 16) & 1u)) >> 16);
}
static __device__ __forceinline__ float bf2f(ushort u) {
    union { unsigned u; float f; } v; v.u = (unsigned)u << 16; return v.f;
}
static __device__ __forceinline__ float sigf(float x) {
    return 1.f / (1.f + __expf(-x));
}

// Wt layout: [cq = cix*4+q][tap][g][lane][8j] (ushort).
// element = bf16(Wk[oc = g*64+q*16+(lane&15)][ic = cix*32+(lane>>4)*8+j][ky][kx])
__global__ void transform_w(const float* __restrict__ Wk, ushort* __restrict__ Wt) {
    const int idx  = blockIdx.x * 256 + threadIdx.x;   // 0..36863
    const int lane = idx & 63;
    const int g    = (idx >> 6) & 3;
    const int r2   = idx >> 8;
    const int tap  = r2 % 9;
    const int cq   = r2 / 9;
    const int q    = cq & 3;
    const int cix  = cq >> 2;
    const int oc   = g * 64 + q * 16 + (lane & 15);
    const int icb  = cix * 32 + (lane >> 4) * 8;
    const int ky   = tap / 3, kx = tap - ky * 3;
    ushort* dst = Wt + (size_t)idx * 8;
    #pragma unroll
    for (int j = 0; j < 8; ++j)
        dst[j] = f2bf(Wk[((size_t)(oc * 128 + icb + j) * 3 + ky) * 3 + kx]);
}

// x (8,16,64,64,64) fp32 NCHW -> xb (8,16,4096,64) bf16 NHWC (per bt volume)
__global__ __launch_bounds__(256) void xconv(const float* __restrict__ x,
                                             ushort* __restrict__ xb) {
    __shared__ ushort T[256 * 66];
    const int tid = threadIdx.x;
    const int pg  = blockIdx.x;        // 16 pixel-groups of 256
    const int bt  = blockIdx.y;        // 128
    const float* xt = x  + (size_t)bt * CHW;
    ushort*      xo = xb + (size_t)bt * CHW;
    const int p0 = pg * 256;
    #pragma unroll
    for (int ch = 0; ch < 64; ++ch)
        T[tid * 66 + ch] = f2bf(xt[(size_t)ch * 4096 + p0 + tid]);
    __syncthreads();
    #pragma unroll
    for (int k = 0; k < 64; ++k) {
        const int item = k * 256 + tid;
        const int px = item >> 6, ch = item & 63;
        xo[(size_t)(p0 + px) * 64 + ch] = T[px * 66 + ch];
    }
}

// stage one 32-channel haloed 18x18 chunk from NHWC bf16 src into LDS buffer.
// COH=true: agent-scope coherent loads (h, written by other blocks this
// kernel). COH=false: plain cached loads (x, weights-era data).
template <bool COH>
static __device__ __forceinline__ void stage_chunk(
    ushort* __restrict__ dst, const ushort* __restrict__ src,
    int tid, int ty0, int tx0) {
    #pragma unroll
    for (int k = 0; k < 11; ++k) {
        const int i = tid + k * 256;
        if (i < 2592) {
            const int p   = i >> 3;
            const int icq = i & 7;
            const int py  = p / 18;
            const int pxl = p - py * 18;
            const int gy  = ty0 + py - 1;
            const int gx  = tx0 + pxl - 1;
            ushort4 v = {0, 0, 0, 0};
            if (((unsigned)gy < 64u) & ((unsigned)gx < 64u)) {
                const size_t off = (size_t)(gy * 64 + gx) * 64 + icq * 4;
                if constexpr (COH) {
                    union { unsigned long long u; ushort4 v4; } cv;
                    cv.u = __hip_atomic_load(
                        (const unsigned long long*)&src[off],
                        __ATOMIC_RELAXED, __HIP_MEMORY_SCOPE_AGENT);
                    v = cv.v4;
                } else {
                    v = *(const ushort4*)&src[off];
                }
            }
            *(ushort4*)&dst[p * 40 + icq * 4] = v;
        }
    }
}

// one 32-ic chunk of the 3x3 conv: 144 MFMAs into acc
static __device__ __forceinline__ void conv_chunk(
    const ushort* __restrict__ cur, const ushort* __restrict__ wb,
    f32x4 (&acc)[4][4], int w, int col, int lane, int q8)
{
    #pragma unroll
    for (int kx = 0; kx < 3; ++kx) {
        bf16x8 arow[6];
        #pragma unroll
        for (int j = 0; j < 6; ++j)
            arow[j] = *(const bf16x8*)&cur[((4 * w + j) * 18 + col + kx) * 40 + q8];
        #pragma unroll
        for (int ky = 0; ky < 3; ++ky) {
            const int tap = ky * 3 + kx;
            bf16x8 bfr[4];
            #pragma unroll
            for (int g = 0; g < 4; ++g)
                bfr[g] = *(const bf16x8*)(wb + (size_t)tap * 2048 + g * 512 + lane * 8);
            #pragma unroll
            for (int g = 0; g < 4; ++g)
                #pragma unroll
                for (int r = 0; r < 4; ++r)
                    acc[r][g] = __builtin_amdgcn_mfma_f32_16x16x32_bf16(
                        arow[r + ky], bfr[g], acc[r][g], 0, 0, 0);
        }
    }
}

// one time step. cur holds x(t)-contribution on entry; completes h-conv,
// gates, h/cell stores, arrives at the barrier, then computes x(t+1) into
// oth during the barrier slack, then waits.
static __device__ __forceinline__ void step_body(
    f32x4 (&cur)[4][4], f32x4 (&oth)[4][4], f32x4 (&cpv)[4],
    ushort* zs, const ushort* hi, ushort* ho, const ushort* xn,
    float* cb, const ushort* wq, unsigned* cnt, int last,
    int tid, int w, int col, int lane, int q8, int ty0, int tx0,
    int gy_, int gx_, int hc0)
{
    ushort* B0 = zs;
    ushort* B1 = zs + ZSZ;

    stage_chunk<true>(B0, hi, tid, ty0, tx0);          // h ch 0-31 (cix2)
    __syncthreads();                                   // B0 ready
    stage_chunk<true>(B1, hi + 32, tid, ty0, tx0);     // h ch 32-63 (cix3)
    conv_chunk(B0, wq + 2 * 73728, cur, w, col, lane, q8);
    __syncthreads();                                   // B1 ready, B0 free
    if (!last) stage_chunk<false>(B0, xn, tid, ty0, tx0);   // x(t+1) ch 0-31
    conv_chunk(B1, wq + 3 * 73728, cur, w, col, lane, q8);
    __syncthreads();                                   // B0 ready, B1 free

    // epilogue: gates + state update; cell stays in registers
    #pragma unroll
    for (int r = 0; r < 4; ++r) {
        const size_t rowbase = ((size_t)(gy_ + r) * 64 + gx_) * 64 + hc0 + col;
        #pragma unroll
        for (int reg = 0; reg < 4; ++reg) {
            const float ci  = cur[r][0][reg];
            const float cf  = cur[r][1][reg];
            const float co  = cur[r][2][reg];
            const float cgv = cur[r][3][reg];
            const float cn  = sigf(cf) * cpv[r][reg] + sigf(ci) * tanhf(cgv);
            const float hn  = sigf(co) * tanhf(cn);
            cpv[r][reg] = cn;
            __hip_atomic_store(&ho[rowbase + (size_t)reg * 64], f2bf(hn),
                               __ATOMIC_RELAXED, __HIP_MEMORY_SCOPE_AGENT);
            if (last) cb[rowbase + (size_t)reg * 64] = cn;
        }
    }
    #pragma unroll
    for (int r = 0; r < 4; ++r)
        #pragma unroll
        for (int g = 0; g < 4; ++g)
            cur[r][g] = (f32x4){0.f, 0.f, 0.f, 0.f};   // becomes oth next step

    if (!last) {
        __syncthreads();                               // drain h stores (vmcnt0)
        if (tid == 0)                                  // ARRIVE
            __hip_atomic_fetch_add(cnt, 1u, __ATOMIC_RELAXED,
                                   __HIP_MEMORY_SCOPE_AGENT);
        // ---- barrier-slack work: x-conv for t+1 into oth ----
        stage_chunk<false>(B1, xn + 32, tid, ty0, tx0);     // x(t+1) ch 32-63
        conv_chunk(B0, wq, oth, w, col, lane, q8);          // cix0
        __syncthreads();                               // B1 ready
        conv_chunk(B1, wq + 73728, oth, w, col, lane, q8);  // cix1
        if (tid == 0) {                                // WAIT
            while (__hip_atomic_load(cnt, __ATOMIC_RELAXED,
                                     __HIP_MEMORY_SCOPE_AGENT) < BBLK)
                __builtin_amdgcn_s_sleep(2);
        }
        __syncthreads();                               // release + LDS reuse
    }
}

__global__ __launch_bounds__(256, 2) void convlstm_all(
    const ushort* __restrict__ xb,    // (8,16,4096,64) bf16 NHWC
    const ushort* __restrict__ Wt,    // fragment-ordered bf16 weights
    ushort*       __restrict__ hb0,   // (8,4096,64) bf16 NHWC ping
    ushort*       __restrict__ hb1,   // (8,4096,64) bf16 NHWC pong
    float*        __restrict__ cell,  // (8,4096,64) fp32 NHWC, final only
    unsigned*     __restrict__ bar)   // 15*8 per-(step,batch) counters, 64B apart
{
    __shared__ __align__(16) ushort zs[2 * ZSZ];      // 51,840 B double buffer

    const int tid  = threadIdx.x;
    const int lane = tid & 63;
    const int w    = tid >> 6;
    const int col  = lane & 15;
    const int quad = lane >> 4;
    const int q8   = quad * 8;

    // decode: q pinned per XCD-pair (bid&7 = XCD under round-robin dispatch);
    // remaining bits -> (tile, b). Locality heuristic only.
    const int bid  = blockIdx.x;
    const int q    = (bid & 7) >> 1;
    const int u    = ((bid >> 3) << 1) | (bid & 1);    // 0..127
    const int tile = u & 15;
    const int b    = u >> 4;

    const int ty0  = (tile >> 2) * 16;
    const int tx0  = (tile & 3) * 16;
    const int hc0  = q * 16;

    ushort* h0 = hb0 + (size_t)b * CHW;
    ushort* h1 = hb1 + (size_t)b * CHW;
    float*  cb = cell + (size_t)b * CHW;

    const int gy_ = ty0 + 4 * w;
    const int gx_ = tx0 + quad * 4;
    const ushort* wq = Wt + (size_t)q * 18432;

    f32x4 accA[4][4], accB[4][4], cpv[4];
    #pragma unroll
    for (int r = 0; r < 4; ++r) {
        cpv[r] = (f32x4){0.f, 0.f, 0.f, 0.f};
        #pragma unroll
        for (int g = 0; g < 4; ++g) {
            accA[r][g] = (f32x4){0.f, 0.f, 0.f, 0.f};
            accB[r][g] = (f32x4){0.f, 0.f, 0.f, 0.f};
        }
    }

    // prologue: x(0)-contribution into accA
    {
        const ushort* xt0 = xb + (size_t)b * 16 * CHW;
        stage_chunk<false>(zs, xt0, tid, ty0, tx0);
        __syncthreads();
        stage_chunk<false>(zs + ZSZ, xt0 + 32, tid, ty0, tx0);
        conv_chunk(zs, wq, accA, w, col, lane, q8);             // cix0
        __syncthreads();
        conv_chunk(zs + ZSZ, wq + 73728, accA, w, col, lane, q8); // cix1
    }

    for (int t = 0; t < 16; ++t) {
        const ushort* hi = (t & 1) ? h1 : h0;   // written at step t-1
        ushort*       ho = (t & 1) ? h0 : h1;
        const ushort* xn = xb + ((size_t)b * 16 + t + 1) * CHW;  // unused at t=15
        unsigned*    cnt = &bar[(t * 8 + b) * 16];
        if (t & 1)
            step_body(accB, accA, cpv, zs, hi, ho, xn, cb, wq, cnt, t == 15,
                      tid, w, col, lane, q8, ty0, tx0, gy_, gx_, hc0);
        else
            step_body(accA, accB, cpv, zs, hi, ho, xn, cb, wq, cnt, t == 15,
                      tid, w, col, lane, q8, ty0, tx0, gy_, gx_, hc0);
    }
}

// NHWC -> NCHW final outputs: d_out = [h fp32 | c fp32], each (8,64,4096)
__global__ __launch_bounds__(256) void conv_out(
    const ushort* __restrict__ hN, const float* __restrict__ cN,
    float* __restrict__ out)
{
    __shared__ float T[64][65];
    const int tid  = threadIdx.x;
    const int pg   = blockIdx.x;        // 64 pixel-groups of 64
    const int b    = blockIdx.y;
    const int tsel = blockIdx.z;        // 0 = h, 1 = c
    const int pix0 = pg * 64;

    #pragma unroll
    for (int k = 0; k < 16; ++k) {
        const int idx = k * 256 + tid;
        const int pl = idx >> 6, ch = idx & 63;
        const size_t src = (size_t)b * CHW + (size_t)(pix0 + pl) * 64 + ch;
        T[pl][ch] = tsel ? cN[src] : bf2f(hN[src]);
    }
    __syncthreads();
    float* base = out + (tsel ? 2097152 : 0);
    #pragma unroll
    for (int k = 0; k < 16; ++k) {
        const int idx = k * 256 + tid;
        const int ch = idx >> 6, pl = idx & 63;
        base[(size_t)b * CHW + (size_t)ch * 4096 + pix0 + pl] = T[pl][ch];
    }
}

extern "C" void kernel_launch(void* const* d_in, const int* in_sizes, int n_in,
                              void* d_out, int out_size, void* d_ws, size_t ws_size,
                              hipStream_t stream) {
    const float* x  = (const float*)d_in[0];
    const float* Wk = (const float*)d_in[1];
    float* out = (float*)d_out;

    char* ws = (char*)d_ws;
    ushort*   Wt  = (ushort*)ws;                       // 589,824 B @ 0
    unsigned* bar = (unsigned*)(ws + 917504);          // 7,680 B @ 896 KB
    float*    cb  = (float*)(ws + (1u << 20));         // 8,388,608 B @ 1 MB
    ushort*   hb0 = (ushort*)(ws + (16u << 20));       // 4,194,304 B @ 16 MB
    ushort*   hb1 = (ushort*)(ws + (20u << 20));       // 4,194,304 B @ 20 MB
    ushort*   xb  = (ushort*)(ws + (32u << 20));       // 67,108,864 B @ 32 MB

    (void)hipMemsetAsync(hb0, 0, 4194304, stream);     // h(-1) = 0
    (void)hipMemsetAsync(bar, 0, 8192, stream);        // barrier counters
    transform_w<<<144, 256, 0, stream>>>(Wk, Wt);
    xconv<<<dim3(16, 128), 256, 0, stream>>>(x, xb);

    convlstm_all<<<512, 256, 0, stream>>>(xb, Wt, hb0, hb1, cb, bar);

    // t=15 wrote hb0
    conv_out<<<dim3(64, 8, 2), 256, 0, stream>>>(hb0, cb, out);
}

// Round 7
// 1652.889 us; speedup vs baseline: 1.4691x; 1.4691x over previous
//
#include <hip/hip_runtime.h>
#include <cmath>

// ConvLSTM round 13b: identical resubmit of round 13 (container infra failure,
// no data). Round-11 kernel with ONE change -- L2-sized XCD grouping.
// r12 post-mortem: q-pinning left 4 batches/XCD -> 5.5 MB/step streaming
// through 4 MB L2 -> weights still evicted every step (FETCH stuck 2.3 GB);
// the acc-bank restructure added spills (+246 MB WRITE) and serialization.
// r13: revert to r11 structure (1439 us, proven), decode bid so each XCD gets
// (q-pair x batch-pair x 16 tiles): stream 2x(0.68+0.68) x/h + 0.29 MB weights
// = 3.0 MB < 4 MB L2 -> weight quarters stay L2-resident across all 16 steps,
// and same-tile q-duplicate x/h reads become L2 hits. Locality-only mapping;
// correctness independent of dispatch (h stays sc1-coherent at IF).

#define CHW 262144             // 64*64*64
#define ZSZ 12960              // ushorts per z buffer (324*40)
#define BBLK 64u               // blocks per batch (16 tiles x 4 quarters)

typedef short bf16x8 __attribute__((ext_vector_type(8)));
typedef float f32x4  __attribute__((ext_vector_type(4)));

static __device__ __forceinline__ ushort f2bf(float f) {
    union { float f; unsigned u; } v; v.f = f;
    unsigned u = v.u;
    return (ushort)((u + 0x7FFFu + ((u >> 16) & 1u)) >> 16);
}
static __device__ __forceinline__ float bf2f(ushort u) {
    union { unsigned u; float f; } v; v.u = (unsigned)u << 16; return v.f;
}
static __device__ __forceinline__ float sigf(float x) {
    return 1.f / (1.f + __expf(-x));
}

// Wt layout: [cq = cix*4+q][tap][g][lane][8j] (ushort).
// element = bf16(Wk[oc = g*64+q*16+(lane&15)][ic = cix*32+(lane>>4)*8+j][ky][kx])
__global__ void transform_w(const float* __restrict__ Wk, ushort* __restrict__ Wt) {
    const int idx  = blockIdx.x * 256 + threadIdx.x;   // 0..36863
    const int lane = idx & 63;
    const int g    = (idx >> 6) & 3;
    const int r2   = idx >> 8;
    const int tap  = r2 % 9;
    const int cq   = r2 / 9;
    const int q    = cq & 3;
    const int cix  = cq >> 2;
    const int oc   = g * 64 + q * 16 + (lane & 15);
    const int icb  = cix * 32 + (lane >> 4) * 8;
    const int ky   = tap / 3, kx = tap - ky * 3;
    ushort* dst = Wt + (size_t)idx * 8;
    #pragma unroll
    for (int j = 0; j < 8; ++j)
        dst[j] = f2bf(Wk[((size_t)(oc * 128 + icb + j) * 3 + ky) * 3 + kx]);
}

// x (8,16,64,64,64) fp32 NCHW -> xb (8,16,4096,64) bf16 NHWC (per bt volume)
__global__ __launch_bounds__(256) void xconv(const float* __restrict__ x,
                                             ushort* __restrict__ xb) {
    __shared__ ushort T[256 * 66];
    const int tid = threadIdx.x;
    const int pg  = blockIdx.x;        // 16 pixel-groups of 256
    const int bt  = blockIdx.y;        // 128
    const float* xt = x  + (size_t)bt * CHW;
    ushort*      xo = xb + (size_t)bt * CHW;
    const int p0 = pg * 256;
    #pragma unroll
    for (int ch = 0; ch < 64; ++ch)
        T[tid * 66 + ch] = f2bf(xt[(size_t)ch * 4096 + p0 + tid]);
    __syncthreads();
    #pragma unroll
    for (int k = 0; k < 64; ++k) {
        const int item = k * 256 + tid;
        const int px = item >> 6, ch = item & 63;
        xo[(size_t)(p0 + px) * 64 + ch] = T[px * 66 + ch];
    }
}

// stage one 32-channel haloed 18x18 chunk from NHWC bf16 src into LDS buffer.
// COH=true: agent-scope coherent loads (h, written by other blocks this
// kernel -- always correct, independent of XCD placement). COH=false: plain
// cached loads (x, weights-era data).
template <bool COH>
static __device__ __forceinline__ void stage_chunk(
    ushort* __restrict__ dst, const ushort* __restrict__ src,
    int tid, int ty0, int tx0) {
    #pragma unroll
    for (int k = 0; k < 11; ++k) {
        const int i = tid + k * 256;
        if (i < 2592) {
            const int p   = i >> 3;
            const int icq = i & 7;
            const int py  = p / 18;
            const int pxl = p - py * 18;
            const int gy  = ty0 + py - 1;
            const int gx  = tx0 + pxl - 1;
            ushort4 v = {0, 0, 0, 0};
            if (((unsigned)gy < 64u) & ((unsigned)gx < 64u)) {
                const size_t off = (size_t)(gy * 64 + gx) * 64 + icq * 4;
                if constexpr (COH) {
                    union { unsigned long long u; ushort4 v4; } cv;
                    cv.u = __hip_atomic_load(
                        (const unsigned long long*)&src[off],
                        __ATOMIC_RELAXED, __HIP_MEMORY_SCOPE_AGENT);
                    v = cv.v4;
                } else {
                    v = *(const ushort4*)&src[off];
                }
            }
            *(ushort4*)&dst[p * 40 + icq * 4] = v;
        }
    }
}

__global__ __launch_bounds__(256, 2) void convlstm_all(
    const ushort* __restrict__ xb,    // (8,16,4096,64) bf16 NHWC
    const ushort* __restrict__ Wt,    // fragment-ordered bf16 weights
    ushort*       __restrict__ hb0,   // (8,4096,64) bf16 NHWC ping
    ushort*       __restrict__ hb1,   // (8,4096,64) bf16 NHWC pong
    float*        __restrict__ cell,  // (8,4096,64) fp32 NHWC, final only
    unsigned*     __restrict__ bar)   // 15*8 per-(step,batch) counters, 64B apart
{
    __shared__ __align__(16) ushort zs[2 * ZSZ];      // 51,840 B double buffer

    const int tid  = threadIdx.x;
    const int lane = tid & 63;
    const int w    = tid >> 6;
    const int col  = lane & 15;
    const int quad = lane >> 4;
    const int q8   = quad * 8;

    // L2-sized XCD grouping (locality heuristic only): under round-robin
    // dispatch, XCD = bid&7. Give each XCD a q-pair x batch-pair x 16 tiles:
    // per-step stream 2x(x+h tile set) + 2 weight quarters ~= 3.0 MB < 4 MB L2
    // -> weights stay resident all 16 steps.
    const int bid  = blockIdx.x;
    const int g8   = bid & 7;                       // XCD
    const int wv   = bid >> 3;                      // 0..63 within XCD
    const int q    = ((g8 >> 2) << 1) | (wv & 1);   // q-pair per XCD
    const int b    = ((g8 & 3) << 1) | ((wv >> 1) & 1); // b-pair per XCD
    const int tile = wv >> 2;                       // 16 tiles

    const int ty0  = (tile >> 2) * 16;
    const int tx0  = (tile & 3) * 16;
    const int hc0  = q * 16;

    ushort* h0 = hb0 + (size_t)b * CHW;
    ushort* h1 = hb1 + (size_t)b * CHW;
    float*  cb = cell + (size_t)b * CHW;

    const int gy_ = ty0 + 4 * w;
    const int gx_ = tx0 + quad * 4;
    const ushort* wq = Wt + (size_t)q * 18432;

    // cell lives in registers across all 16 steps
    f32x4 cpv[4];
    #pragma unroll
    for (int r = 0; r < 4; ++r)
        cpv[r] = (f32x4){0.f, 0.f, 0.f, 0.f};

    for (int t = 0; t < 16; ++t) {
        const ushort* xt = xb + ((size_t)b * 16 + t) * CHW;
        const ushort* hi = (t & 1) ? h1 : h0;   // written at step t-1
        ushort*       ho = (t & 1) ? h0 : h1;

        f32x4 acc[4][4];
        #pragma unroll
        for (int r = 0; r < 4; ++r)
            #pragma unroll
            for (int g = 0; g < 4; ++g)
                acc[r][g] = (f32x4){0.f, 0.f, 0.f, 0.f};

        // chunk sources: 0,1 -> x channels 0-31/32-63; 2,3 -> h channels 0-31/32-63
        stage_chunk<false>(zs, xt, tid, ty0, tx0);
        __syncthreads();

        #pragma unroll
        for (int cix = 0; cix < 4; ++cix) {
            ushort* cur = zs + (cix & 1) * ZSZ;
            ushort* nxt = zs + ((cix + 1) & 1) * ZSZ;

            // stage next chunk into the idle buffer (no barrier: nxt unread
            // this iter); compiler interleaves these with the MFMAs below.
            if (cix == 0) stage_chunk<false>(nxt, xt + 32, tid, ty0, tx0);
            else if (cix == 1) stage_chunk<true>(nxt, hi, tid, ty0, tx0);
            else if (cix == 2) stage_chunk<true>(nxt, hi + 32, tid, ty0, tx0);

            const ushort* wb = wq + (size_t)cix * 4 * 18432;
            #pragma unroll
            for (int kx = 0; kx < 3; ++kx) {
                bf16x8 arow[6];
                #pragma unroll
                for (int j = 0; j < 6; ++j)
                    arow[j] = *(const bf16x8*)&cur[((4 * w + j) * 18 + col + kx) * 40 + q8];
                #pragma unroll
                for (int ky = 0; ky < 3; ++ky) {
                    const int tap = ky * 3 + kx;
                    bf16x8 bfr[4];
                    #pragma unroll
                    for (int g = 0; g < 4; ++g)
                        bfr[g] = *(const bf16x8*)(wb + (size_t)tap * 2048 + g * 512 + lane * 8);
                    #pragma unroll
                    for (int g = 0; g < 4; ++g)
                        #pragma unroll
                        for (int r = 0; r < 4; ++r)
                            acc[r][g] = __builtin_amdgcn_mfma_f32_16x16x32_bf16(
                                arow[r + ky], bfr[g], acc[r][g], 0, 0, 0);
                }
            }
            __syncthreads();   // nxt fully written & cur fully read before swap
        }

        // epilogue: gates + state update; cell stays in registers.
        // h stores are agent-scope write-through (visible at IF, no fence).
        #pragma unroll
        for (int r = 0; r < 4; ++r) {
            const size_t rowbase = ((size_t)(gy_ + r) * 64 + gx_) * 64 + hc0 + col;
            #pragma unroll
            for (int reg = 0; reg < 4; ++reg) {
                const float ci  = acc[r][0][reg];
                const float cf  = acc[r][1][reg];
                const float co  = acc[r][2][reg];
                const float cgv = acc[r][3][reg];
                const float cn  = sigf(cf) * cpv[r][reg] + sigf(ci) * tanhf(cgv);
                const float hn  = sigf(co) * tanhf(cn);
                cpv[r][reg] = cn;
                __hip_atomic_store(&ho[rowbase + (size_t)reg * 64], f2bf(hn),
                                   __ATOMIC_RELAXED, __HIP_MEMORY_SCOPE_AGENT);
                if (t == 15) cb[rowbase + (size_t)reg * 64] = cn;
            }
        }

        if (t < 15) {
            // ---- per-batch grid barrier, counter-only, no fences ----
            // __syncthreads drains each wave's h stores (vmcnt(0)) to the IF
            // coherence point BEFORE tid0 arrives; readers use sc1 loads.
            __syncthreads();
            if (tid == 0) {
                unsigned* c = &bar[(t * 8 + b) * 16];   // 64B-padded counter
                __hip_atomic_fetch_add(c, 1u, __ATOMIC_RELAXED,
                                       __HIP_MEMORY_SCOPE_AGENT);
                while (__hip_atomic_load(c, __ATOMIC_RELAXED,
                                         __HIP_MEMORY_SCOPE_AGENT) < BBLK)
                    __builtin_amdgcn_s_sleep(2);
            }
            __syncthreads();
        }
    }
}

// NHWC -> NCHW final outputs: d_out = [h fp32 | c fp32], each (8,64,4096)
__global__ __launch_bounds__(256) void conv_out(
    const ushort* __restrict__ hN, const float* __restrict__ cN,
    float* __restrict__ out)
{
    __shared__ float T[64][65];
    const int tid  = threadIdx.x;
    const int pg   = blockIdx.x;        // 64 pixel-groups of 64
    const int b    = blockIdx.y;
    const int tsel = blockIdx.z;        // 0 = h, 1 = c
    const int pix0 = pg * 64;

    #pragma unroll
    for (int k = 0; k < 16; ++k) {
        const int idx = k * 256 + tid;
        const int pl = idx >> 6, ch = idx & 63;
        const size_t src = (size_t)b * CHW + (size_t)(pix0 + pl) * 64 + ch;
        T[pl][ch] = tsel ? cN[src] : bf2f(hN[src]);
    }
    __syncthreads();
    float* base = out + (tsel ? 2097152 : 0);
    #pragma unroll
    for (int k = 0; k < 16; ++k) {
        const int idx = k * 256 + tid;
        const int ch = idx >> 6, pl = idx & 63;
        base[(size_t)b * CHW + (size_t)ch * 4096 + pix0 + pl] = T[pl][ch];
    }
}

extern "C" void kernel_launch(void* const* d_in, const int* in_sizes, int n_in,
                              void* d_out, int out_size, void* d_ws, size_t ws_size,
                              hipStream_t stream) {
    const float* x  = (const float*)d_in[0];
    const float* Wk = (const float*)d_in[1];
    float* out = (float*)d_out;

    char* ws = (char*)d_ws;
    ushort*   Wt  = (ushort*)ws;                       // 589,824 B @ 0
    unsigned* bar = (unsigned*)(ws + 917504);          // 7,680 B @ 896 KB
    float*    cb  = (float*)(ws + (1u << 20));         // 8,388,608 B @ 1 MB
    ushort*   hb0 = (ushort*)(ws + (16u << 20));       // 4,194,304 B @ 16 MB
    ushort*   hb1 = (ushort*)(ws + (20u << 20));       // 4,194,304 B @ 20 MB
    ushort*   xb  = (ushort*)(ws + (32u << 20));       // 67,108,864 B @ 32 MB

    (void)hipMemsetAsync(hb0, 0, 4194304, stream);     // h(-1) = 0
    (void)hipMemsetAsync(bar, 0, 8192, stream);        // barrier counters
    transform_w<<<144, 256, 0, stream>>>(Wk, Wt);
    xconv<<<dim3(16, 128), 256, 0, stream>>>(x, xb);

    convlstm_all<<<512, 256, 0, stream>>>(xb, Wt, hb0, hb1, cb, bar);

    // t=15 wrote hb0
    conv_out<<<dim3(64, 8, 2), 256, 0, stream>>>(hb0, cb, out);
}

// Round 8
// 1447.222 us; speedup vs baseline: 1.6778x; 1.1421x over previous
//
#include <hip/hip_runtime.h>
#include <cmath>

// ConvLSTM round 14: VERIFIED XCD-local fast path for h, measured not assumed.
// r13 post-mortem: two different bid->XCD groupings produced ZERO FETCH delta
// (2.35 vs 2.45 GB) -> the bid%8=XCD assumption is untested and the L2 model
// has a hole. This round measures placement directly: each block reads
// HW_REG_XCC_ID (m09-verified on gfx950), publishes into a per-batch mask;
// popcount==1 -> batch provably XCD-local -> h via PLAIN L2-local loads/stores
// + per-step buffer_inv sc0 (L1-ONLY invalidate; L2 stays warm, unlike r9's
// agent fence) to kill L1 staleness (incl. stale lines from prior graph
// replay). Else -> r11's proven sc1 path (bit-identical values).
// Also: s_sleep(16) in spins (8x less sc1 poll traffic through the fabric).

#define CHW 262144             // 64*64*64
#define ZSZ 12960              // ushorts per z buffer (324*40)
#define BBLK 64u               // blocks per batch (16 tiles x 4 quarters)

typedef short bf16x8 __attribute__((ext_vector_type(8)));
typedef float f32x4  __attribute__((ext_vector_type(4)));

static __device__ __forceinline__ ushort f2bf(float f) {
    union { float f; unsigned u; } v; v.f = f;
    unsigned u = v.u;
    return (ushort)((u + 0x7FFFu + ((u >> 16) & 1u)) >> 16);
}
static __device__ __forceinline__ float bf2f(ushort u) {
    union { unsigned u; float f; } v; v.u = (unsigned)u << 16; return v.f;
}
static __device__ __forceinline__ float sigf(float x) {
    return 1.f / (1.f + __expf(-x));
}

// Wt layout: [cq = cix*4+q][tap][g][lane][8j] (ushort).
// element = bf16(Wk[oc = g*64+q*16+(lane&15)][ic = cix*32+(lane>>4)*8+j][ky][kx])
__global__ void transform_w(const float* __restrict__ Wk, ushort* __restrict__ Wt) {
    const int idx  = blockIdx.x * 256 + threadIdx.x;   // 0..36863
    const int lane = idx & 63;
    const int g    = (idx >> 6) & 3;
    const int r2   = idx >> 8;
    const int tap  = r2 % 9;
    const int cq   = r2 / 9;
    const int q    = cq & 3;
    const int cix  = cq >> 2;
    const int oc   = g * 64 + q * 16 + (lane & 15);
    const int icb  = cix * 32 + (lane >> 4) * 8;
    const int ky   = tap / 3, kx = tap - ky * 3;
    ushort* dst = Wt + (size_t)idx * 8;
    #pragma unroll
    for (int j = 0; j < 8; ++j)
        dst[j] = f2bf(Wk[((size_t)(oc * 128 + icb + j) * 3 + ky) * 3 + kx]);
}

// x (8,16,64,64,64) fp32 NCHW -> xb (8,16,4096,64) bf16 NHWC (per bt volume)
__global__ __launch_bounds__(256) void xconv(const float* __restrict__ x,
                                             ushort* __restrict__ xb) {
    __shared__ ushort T[256 * 66];
    const int tid = threadIdx.x;
    const int pg  = blockIdx.x;        // 16 pixel-groups of 256
    const int bt  = blockIdx.y;        // 128
    const float* xt = x  + (size_t)bt * CHW;
    ushort*      xo = xb + (size_t)bt * CHW;
    const int p0 = pg * 256;
    #pragma unroll
    for (int ch = 0; ch < 64; ++ch)
        T[tid * 66 + ch] = f2bf(xt[(size_t)ch * 4096 + p0 + tid]);
    __syncthreads();
    #pragma unroll
    for (int k = 0; k < 64; ++k) {
        const int item = k * 256 + tid;
        const int px = item >> 6, ch = item & 63;
        xo[(size_t)(p0 + px) * 64 + ch] = T[px * 66 + ch];
    }
}

// stage one 32-channel haloed 18x18 chunk from NHWC bf16 src into LDS buffer.
// COH=true: agent-scope (sc1, IF-coherent) loads -- h on the slow path.
// COH=false: plain cached loads -- x, weights, and h on the verified-local path.
template <bool COH>
static __device__ __forceinline__ void stage_chunk(
    ushort* __restrict__ dst, const ushort* __restrict__ src,
    int tid, int ty0, int tx0) {
    #pragma unroll
    for (int k = 0; k < 11; ++k) {
        const int i = tid + k * 256;
        if (i < 2592) {
            const int p   = i >> 3;
            const int icq = i & 7;
            const int py  = p / 18;
            const int pxl = p - py * 18;
            const int gy  = ty0 + py - 1;
            const int gx  = tx0 + pxl - 1;
            ushort4 v = {0, 0, 0, 0};
            if (((unsigned)gy < 64u) & ((unsigned)gx < 64u)) {
                const size_t off = (size_t)(gy * 64 + gx) * 64 + icq * 4;
                if constexpr (COH) {
                    union { unsigned long long u; ushort4 v4; } cv;
                    cv.u = __hip_atomic_load(
                        (const unsigned long long*)&src[off],
                        __ATOMIC_RELAXED, __HIP_MEMORY_SCOPE_AGENT);
                    v = cv.v4;
                } else {
                    v = *(const ushort4*)&src[off];
                }
            }
            *(ushort4*)&dst[p * 40 + icq * 4] = v;
        }
    }
}

__global__ __launch_bounds__(256, 2) void convlstm_all(
    const ushort* __restrict__ xb,    // (8,16,4096,64) bf16 NHWC
    const ushort* __restrict__ Wt,    // fragment-ordered bf16 weights
    ushort*       __restrict__ hb0,   // (8,4096,64) bf16 NHWC ping
    ushort*       __restrict__ hb1,   // (8,4096,64) bf16 NHWC pong
    float*        __restrict__ cell,  // (8,4096,64) fp32 NHWC, final only
    unsigned*     __restrict__ bar)   // counters + XCC masks (see layout below)
{
    __shared__ __align__(16) ushort zs[2 * ZSZ];      // 51,840 B double buffer
    __shared__ int sflag;

    const int tid  = threadIdx.x;
    const int lane = tid & 63;
    const int w    = tid >> 6;
    const int col  = lane & 15;
    const int quad = lane >> 4;
    const int q8   = quad * 8;

    // r11 decode: b fastest (batch<->XCD 1:1 IF dispatch is round-robin --
    // which we VERIFY below instead of assuming).
    const int bid  = blockIdx.x;
    const int b    = bid & 7;
    const int tile = (bid >> 3) & 15;
    const int q    = bid >> 7;

    const int ty0  = (tile >> 2) * 16;
    const int tx0  = (tile & 3) * 16;
    const int hc0  = q * 16;

    ushort* h0 = hb0 + (size_t)b * CHW;
    ushort* h1 = hb1 + (size_t)b * CHW;
    float*  cb = cell + (size_t)b * CHW;

    const int gy_ = ty0 + 4 * w;
    const int gx_ = tx0 + quad * 4;
    const ushort* wq = Wt + (size_t)q * 18432;

    // ---- one-time XCD-locality verification ----
    // bar layout (unsigned words): (t*8+b)*16 step counters (t<15);
    // (120+b)*16 start counters; 2048 + b*16 XCC masks.
    unsigned xcc;
    asm("s_getreg_b32 %0, hwreg(HW_REG_XCC_ID)" : "=s"(xcc));
    xcc &= 7u;
    if (tid == 0) {
        unsigned* xm   = bar + 2048 + b * 16;
        unsigned* scnt = bar + (120 + b) * 16;
        __hip_atomic_fetch_or(xm, 1u << xcc, __ATOMIC_RELAXED,
                              __HIP_MEMORY_SCOPE_AGENT);
        // RELEASE: the or above is visible before this arrive is.
        __hip_atomic_fetch_add(scnt, 1u, __ATOMIC_RELEASE,
                               __HIP_MEMORY_SCOPE_AGENT);
        while (__hip_atomic_load(scnt, __ATOMIC_RELAXED,
                                 __HIP_MEMORY_SCOPE_AGENT) < BBLK)
            __builtin_amdgcn_s_sleep(16);
        unsigned m = __hip_atomic_load(xm, __ATOMIC_ACQUIRE,
                                       __HIP_MEMORY_SCOPE_AGENT);
        sflag = (__popc(m) == 1);
    }
    __syncthreads();
    const bool fast = (sflag != 0);

    // cell lives in registers across all 16 steps
    f32x4 cpv[4];
    #pragma unroll
    for (int r = 0; r < 4; ++r)
        cpv[r] = (f32x4){0.f, 0.f, 0.f, 0.f};

    for (int t = 0; t < 16; ++t) {
        // Fast path: L1-only invalidate (sc1=0 -> L2 untouched) so plain h
        // loads can't hit stale L1 lines (incl. lines left by the previous
        // graph replay). Producer h stores are already in L2 (write-through
        // L1 + vmcnt(0) drain at the pre-arrive __syncthreads).
        if (fast)
            asm volatile("buffer_inv sc0\n\ts_waitcnt vmcnt(0)" ::: "memory");

        const ushort* xt = xb + ((size_t)b * 16 + t) * CHW;
        const ushort* hi = (t & 1) ? h1 : h0;   // written at step t-1
        ushort*       ho = (t & 1) ? h0 : h1;

        f32x4 acc[4][4];
        #pragma unroll
        for (int r = 0; r < 4; ++r)
            #pragma unroll
            for (int g = 0; g < 4; ++g)
                acc[r][g] = (f32x4){0.f, 0.f, 0.f, 0.f};

        // chunk sources: 0,1 -> x channels 0-31/32-63; 2,3 -> h channels 0-31/32-63
        stage_chunk<false>(zs, xt, tid, ty0, tx0);
        __syncthreads();

        #pragma unroll
        for (int cix = 0; cix < 4; ++cix) {
            ushort* cur = zs + (cix & 1) * ZSZ;
            ushort* nxt = zs + ((cix + 1) & 1) * ZSZ;

            // stage next chunk into the idle buffer (no barrier: nxt unread
            // this iter); compiler interleaves these with the MFMAs below.
            if (cix == 0) stage_chunk<false>(nxt, xt + 32, tid, ty0, tx0);
            else if (cix == 1) {
                if (fast) stage_chunk<false>(nxt, hi, tid, ty0, tx0);
                else      stage_chunk<true >(nxt, hi, tid, ty0, tx0);
            } else if (cix == 2) {
                if (fast) stage_chunk<false>(nxt, hi + 32, tid, ty0, tx0);
                else      stage_chunk<true >(nxt, hi + 32, tid, ty0, tx0);
            }

            const ushort* wb = wq + (size_t)cix * 4 * 18432;
            #pragma unroll
            for (int kx = 0; kx < 3; ++kx) {
                bf16x8 arow[6];
                #pragma unroll
                for (int j = 0; j < 6; ++j)
                    arow[j] = *(const bf16x8*)&cur[((4 * w + j) * 18 + col + kx) * 40 + q8];
                #pragma unroll
                for (int ky = 0; ky < 3; ++ky) {
                    const int tap = ky * 3 + kx;
                    bf16x8 bfr[4];
                    #pragma unroll
                    for (int g = 0; g < 4; ++g)
                        bfr[g] = *(const bf16x8*)(wb + (size_t)tap * 2048 + g * 512 + lane * 8);
                    #pragma unroll
                    for (int g = 0; g < 4; ++g)
                        #pragma unroll
                        for (int r = 0; r < 4; ++r)
                            acc[r][g] = __builtin_amdgcn_mfma_f32_16x16x32_bf16(
                                arow[r + ky], bfr[g], acc[r][g], 0, 0, 0);
                }
            }
            __syncthreads();   // nxt fully written & cur fully read before swap
        }

        // epilogue: gates + state update; cell stays in registers.
        ushort hsv[4][4];
        #pragma unroll
        for (int r = 0; r < 4; ++r) {
            #pragma unroll
            for (int reg = 0; reg < 4; ++reg) {
                const float ci  = acc[r][0][reg];
                const float cf  = acc[r][1][reg];
                const float co  = acc[r][2][reg];
                const float cgv = acc[r][3][reg];
                const float cn  = sigf(cf) * cpv[r][reg] + sigf(ci) * tanhf(cgv);
                cpv[r][reg] = cn;
                hsv[r][reg] = f2bf(sigf(co) * tanhf(cn));
            }
        }
        if (fast) {
            #pragma unroll
            for (int r = 0; r < 4; ++r) {
                const size_t rowbase = ((size_t)(gy_ + r) * 64 + gx_) * 64 + hc0 + col;
                #pragma unroll
                for (int reg = 0; reg < 4; ++reg)
                    ho[rowbase + (size_t)reg * 64] = hsv[r][reg];
            }
        } else {
            #pragma unroll
            for (int r = 0; r < 4; ++r) {
                const size_t rowbase = ((size_t)(gy_ + r) * 64 + gx_) * 64 + hc0 + col;
                #pragma unroll
                for (int reg = 0; reg < 4; ++reg)
                    __hip_atomic_store(&ho[rowbase + (size_t)reg * 64], hsv[r][reg],
                                       __ATOMIC_RELAXED, __HIP_MEMORY_SCOPE_AGENT);
            }
        }
        if (t == 15) {
            #pragma unroll
            for (int r = 0; r < 4; ++r) {
                const size_t rowbase = ((size_t)(gy_ + r) * 64 + gx_) * 64 + hc0 + col;
                #pragma unroll
                for (int reg = 0; reg < 4; ++reg)
                    cb[rowbase + (size_t)reg * 64] = cpv[r][reg];
            }
        }

        if (t < 15) {
            // ---- per-batch grid barrier, counter-only ----
            // __syncthreads drains each wave's h stores (vmcnt(0)) BEFORE
            // tid0 arrives; fast-path readers re-read from L2 after the
            // per-step L1 inv, slow-path readers use sc1/IF loads.
            __syncthreads();
            if (tid == 0) {
                unsigned* c = &bar[(t * 8 + b) * 16];   // 64B-padded counter
                __hip_atomic_fetch_add(c, 1u, __ATOMIC_RELAXED,
                                       __HIP_MEMORY_SCOPE_AGENT);
                while (__hip_atomic_load(c, __ATOMIC_RELAXED,
                                         __HIP_MEMORY_SCOPE_AGENT) < BBLK)
                    __builtin_amdgcn_s_sleep(16);
            }
            __syncthreads();
        }
    }
}

// NHWC -> NCHW final outputs: d_out = [h fp32 | c fp32], each (8,64,4096)
__global__ __launch_bounds__(256) void conv_out(
    const ushort* __restrict__ hN, const float* __restrict__ cN,
    float* __restrict__ out)
{
    __shared__ float T[64][65];
    const int tid  = threadIdx.x;
    const int pg   = blockIdx.x;        // 64 pixel-groups of 64
    const int b    = blockIdx.y;
    const int tsel = blockIdx.z;        // 0 = h, 1 = c
    const int pix0 = pg * 64;

    #pragma unroll
    for (int k = 0; k < 16; ++k) {
        const int idx = k * 256 + tid;
        const int pl = idx >> 6, ch = idx & 63;
        const size_t src = (size_t)b * CHW + (size_t)(pix0 + pl) * 64 + ch;
        T[pl][ch] = tsel ? cN[src] : bf2f(hN[src]);
    }
    __syncthreads();
    float* base = out + (tsel ? 2097152 : 0);
    #pragma unroll
    for (int k = 0; k < 16; ++k) {
        const int idx = k * 256 + tid;
        const int ch = idx >> 6, pl = idx & 63;
        base[(size_t)b * CHW + (size_t)ch * 4096 + pix0 + pl] = T[pl][ch];
    }
}

extern "C" void kernel_launch(void* const* d_in, const int* in_sizes, int n_in,
                              void* d_out, int out_size, void* d_ws, size_t ws_size,
                              hipStream_t stream) {
    const float* x  = (const float*)d_in[0];
    const float* Wk = (const float*)d_in[1];
    float* out = (float*)d_out;

    char* ws = (char*)d_ws;
    ushort*   Wt  = (ushort*)ws;                       // 589,824 B @ 0
    unsigned* bar = (unsigned*)(ws + 917504);          // 16,384 B @ 896 KB
    float*    cb  = (float*)(ws + (1u << 20));         // 8,388,608 B @ 1 MB
    ushort*   hb0 = (ushort*)(ws + (16u << 20));       // 4,194,304 B @ 16 MB
    ushort*   hb1 = (ushort*)(ws + (20u << 20));       // 4,194,304 B @ 20 MB
    ushort*   xb  = (ushort*)(ws + (32u << 20));       // 67,108,864 B @ 32 MB

    (void)hipMemsetAsync(hb0, 0, 4194304, stream);     // h(-1) = 0
    (void)hipMemsetAsync(bar, 0, 16384, stream);       // counters + masks
    transform_w<<<144, 256, 0, stream>>>(Wk, Wt);
    xconv<<<dim3(16, 128), 256, 0, stream>>>(x, xb);

    convlstm_all<<<512, 256, 0, stream>>>(xb, Wt, hb0, hb1, cb, bar);

    // t=15 wrote hb0
    conv_out<<<dim3(64, 8, 2), 256, 0, stream>>>(hb0, cb, out);
}

// Round 9
// 799.148 us; speedup vs baseline: 3.0385x; 1.8110x over previous
//
#include <hip/hip_runtime.h>
#include <cmath>

// ConvLSTM round 15: gate-per-wave weight residency on the r14 skeleton.
// r14 post-mortem: fast path engaged (FETCH 2.45->1.08 GB) but still
// latency-bound at 79 us/step vs 8 us compute floor. Audit: every wave was
// loading ALL 4 gates' weight fragments (144 x 1KB x 4 waves = 590 KB/block/
// step, 4.8 GB requested, ~1.1 GB missing to HBM *on the critical path*).
// Fix: wave w owns gate w for all 16 rows -> 36 frags/wave; h-weights
// (cix 2,3) live in REGISTERS across all 16 steps (72 VGPRs, zero loads in
// the post-barrier critical phases); x-weights are 9 hoisted L2-warm loads
// per phase. Phase order h-first (cix 2,3,0,1) = summation reorder only.
// Epilogue: 2-half LDS gate exchange in the freed z buffers (32 KB).
// Everything else (XCC-verified fast/slow h path, counters, s_sleep(16),
// 512 blocks x 256 thr, lb(256,2)) kept verbatim from r14.

#define CHW 262144             // 64*64*64
#define ZSZ 12960              // ushorts per z buffer (324*40)
#define BBLK 64u               // blocks per batch (16 tiles x 4 quarters)

typedef short bf16x8 __attribute__((ext_vector_type(8)));
typedef float f32x4  __attribute__((ext_vector_type(4)));

static __device__ __forceinline__ ushort f2bf(float f) {
    union { float f; unsigned u; } v; v.f = f;
    unsigned u = v.u;
    return (ushort)((u + 0x7FFFu + ((u >> 16) & 1u)) >> 16);
}
static __device__ __forceinline__ float bf2f(ushort u) {
    union { unsigned u; float f; } v; v.u = (unsigned)u << 16; return v.f;
}
static __device__ __forceinline__ float sigf(float x) {
    return 1.f / (1.f + __expf(-x));
}

// Wt layout: [cq = cix*4+q][tap][g][lane][8j] (ushort).
// element = bf16(Wk[oc = g*64+q*16+(lane&15)][ic = cix*32+(lane>>4)*8+j][ky][kx])
__global__ void transform_w(const float* __restrict__ Wk, ushort* __restrict__ Wt) {
    const int idx  = blockIdx.x * 256 + threadIdx.x;   // 0..36863
    const int lane = idx & 63;
    const int g    = (idx >> 6) & 3;
    const int r2   = idx >> 8;
    const int tap  = r2 % 9;
    const int cq   = r2 / 9;
    const int q    = cq & 3;
    const int cix  = cq >> 2;
    const int oc   = g * 64 + q * 16 + (lane & 15);
    const int icb  = cix * 32 + (lane >> 4) * 8;
    const int ky   = tap / 3, kx = tap - ky * 3;
    ushort* dst = Wt + (size_t)idx * 8;
    #pragma unroll
    for (int j = 0; j < 8; ++j)
        dst[j] = f2bf(Wk[((size_t)(oc * 128 + icb + j) * 3 + ky) * 3 + kx]);
}

// x (8,16,64,64,64) fp32 NCHW -> xb (8,16,4096,64) bf16 NHWC (per bt volume)
__global__ __launch_bounds__(256) void xconv(const float* __restrict__ x,
                                             ushort* __restrict__ xb) {
    __shared__ ushort T[256 * 66];
    const int tid = threadIdx.x;
    const int pg  = blockIdx.x;        // 16 pixel-groups of 256
    const int bt  = blockIdx.y;        // 128
    const float* xt = x  + (size_t)bt * CHW;
    ushort*      xo = xb + (size_t)bt * CHW;
    const int p0 = pg * 256;
    #pragma unroll
    for (int ch = 0; ch < 64; ++ch)
        T[tid * 66 + ch] = f2bf(xt[(size_t)ch * 4096 + p0 + tid]);
    __syncthreads();
    #pragma unroll
    for (int k = 0; k < 64; ++k) {
        const int item = k * 256 + tid;
        const int px = item >> 6, ch = item & 63;
        xo[(size_t)(p0 + px) * 64 + ch] = T[px * 66 + ch];
    }
}

// stage one 32-channel haloed 18x18 chunk from NHWC bf16 src into LDS buffer.
// COH=true: agent-scope (sc1, IF-coherent) loads -- h on the slow path.
// COH=false: plain cached loads -- x, weights, and h on the verified-local path.
template <bool COH>
static __device__ __forceinline__ void stage_chunk(
    ushort* __restrict__ dst, const ushort* __restrict__ src,
    int tid, int ty0, int tx0) {
    #pragma unroll
    for (int k = 0; k < 11; ++k) {
        const int i = tid + k * 256;
        if (i < 2592) {
            const int p   = i >> 3;
            const int icq = i & 7;
            const int py  = p / 18;
            const int pxl = p - py * 18;
            const int gy  = ty0 + py - 1;
            const int gx  = tx0 + pxl - 1;
            ushort4 v = {0, 0, 0, 0};
            if (((unsigned)gy < 64u) & ((unsigned)gx < 64u)) {
                const size_t off = (size_t)(gy * 64 + gx) * 64 + icq * 4;
                if constexpr (COH) {
                    union { unsigned long long u; ushort4 v4; } cv;
                    cv.u = __hip_atomic_load(
                        (const unsigned long long*)&src[off],
                        __ATOMIC_RELAXED, __HIP_MEMORY_SCOPE_AGENT);
                    v = cv.v4;
                } else {
                    v = *(const ushort4*)&src[off];
                }
            }
            *(ushort4*)&dst[p * 40 + icq * 4] = v;
        }
    }
}

// one 32-ch chunk of the 3x3 conv for ONE gate: 144 MFMAs into acc[16].
// wf[tap] is this wave's gate fragment (registers).
static __device__ __forceinline__ void conv_gate(
    const ushort* __restrict__ cur, const bf16x8 (&wf)[9],
    f32x4 (&acc)[16], int col, int q8)
{
    #pragma unroll
    for (int rb = 0; rb < 4; ++rb) {
        #pragma unroll
        for (int kx = 0; kx < 3; ++kx) {
            bf16x8 arow[6];
            #pragma unroll
            for (int j = 0; j < 6; ++j)
                arow[j] = *(const bf16x8*)&cur[((4 * rb + j) * 18 + col + kx) * 40 + q8];
            #pragma unroll
            for (int ky = 0; ky < 3; ++ky) {
                const int tap = ky * 3 + kx;
                #pragma unroll
                for (int r = 0; r < 4; ++r)
                    acc[4 * rb + r] = __builtin_amdgcn_mfma_f32_16x16x32_bf16(
                        arow[r + ky], wf[tap], acc[4 * rb + r], 0, 0, 0);
            }
        }
    }
}

__global__ __launch_bounds__(256, 2) void convlstm_all(
    const ushort* __restrict__ xb,    // (8,16,4096,64) bf16 NHWC
    const ushort* __restrict__ Wt,    // fragment-ordered bf16 weights
    ushort*       __restrict__ hb0,   // (8,4096,64) bf16 NHWC ping
    ushort*       __restrict__ hb1,   // (8,4096,64) bf16 NHWC pong
    float*        __restrict__ cell,  // (8,4096,64) fp32 NHWC, final only
    unsigned*     __restrict__ bar)   // counters + XCC masks
{
    __shared__ __align__(16) ushort zs[2 * ZSZ];      // 51,840 B
    __shared__ int sflag;

    const int tid  = threadIdx.x;
    const int lane = tid & 63;
    const int w    = tid >> 6;          // wave index == GATE index
    const int col  = lane & 15;
    const int quad = lane >> 4;
    const int q8   = quad * 8;

    const int bid  = blockIdx.x;
    const int b    = bid & 7;
    const int tile = (bid >> 3) & 15;
    const int q    = bid >> 7;

    const int ty0  = (tile >> 2) * 16;
    const int tx0  = (tile & 3) * 16;
    const int hc0  = q * 16;

    ushort* h0 = hb0 + (size_t)b * CHW;
    ushort* h1 = hb1 + (size_t)b * CHW;
    float*  cb = cell + (size_t)b * CHW;

    const int gx_ = tx0 + quad * 4;
    const ushort* wq = Wt + (size_t)q * 18432;

    // ---- one-time XCD-locality verification (r14) ----
    unsigned xcc;
    asm("s_getreg_b32 %0, hwreg(HW_REG_XCC_ID)" : "=s"(xcc));
    xcc &= 7u;
    if (tid == 0) {
        unsigned* xm   = bar + 2048 + b * 16;
        unsigned* scnt = bar + (120 + b) * 16;
        __hip_atomic_fetch_or(xm, 1u << xcc, __ATOMIC_RELAXED,
                              __HIP_MEMORY_SCOPE_AGENT);
        __hip_atomic_fetch_add(scnt, 1u, __ATOMIC_RELEASE,
                               __HIP_MEMORY_SCOPE_AGENT);
        while (__hip_atomic_load(scnt, __ATOMIC_RELAXED,
                                 __HIP_MEMORY_SCOPE_AGENT) < BBLK)
            __builtin_amdgcn_s_sleep(16);
        unsigned m = __hip_atomic_load(xm, __ATOMIC_ACQUIRE,
                                       __HIP_MEMORY_SCOPE_AGENT);
        sflag = (__popc(m) == 1);
    }
    __syncthreads();
    const bool fast = (sflag != 0);

    // h-weights (cix 2,3) for THIS gate: resident all 16 steps. 72 VGPRs.
    bf16x8 wfh[2][9];
    #pragma unroll
    for (int c = 0; c < 2; ++c)
        #pragma unroll
        for (int tap = 0; tap < 9; ++tap)
            wfh[c][tap] = *(const bf16x8*)(wq + (size_t)(c + 2) * 73728
                                           + tap * 2048 + w * 512 + lane * 8);

    // cell ownership per wave: rows {2w, 2w+1, 2w+8, 2w+9} (fixed relabeling)
    f32x4 cpv[4];
    #pragma unroll
    for (int r = 0; r < 4; ++r)
        cpv[r] = (f32x4){0.f, 0.f, 0.f, 0.f};

    for (int t = 0; t < 16; ++t) {
        if (fast)
            asm volatile("buffer_inv sc0\n\ts_waitcnt vmcnt(0)" ::: "memory");

        const ushort* xt = xb + ((size_t)b * 16 + t) * CHW;
        const ushort* hi = (t & 1) ? h1 : h0;   // written at step t-1
        ushort*       ho = (t & 1) ? h0 : h1;

        f32x4 acc16[16];
        #pragma unroll
        for (int r = 0; r < 16; ++r)
            acc16[r] = (f32x4){0.f, 0.f, 0.f, 0.f};

        ushort* B0 = zs;
        ushort* B1 = zs + ZSZ;

        // phase order: h chunks first (critical data), then x chunks.
        if (fast) stage_chunk<false>(B0, hi, tid, ty0, tx0);
        else      stage_chunk<true >(B0, hi, tid, ty0, tx0);
        __syncthreads();

        // cix2 (h ch 0-31, reg weights) | stage h ch 32-63
        if (fast) stage_chunk<false>(B1, hi + 32, tid, ty0, tx0);
        else      stage_chunk<true >(B1, hi + 32, tid, ty0, tx0);
        conv_gate(B0, wfh[0], acc16, col, q8);
        __syncthreads();

        // cix3 (h ch 32-63, reg weights) | stage x ch 0-31
        stage_chunk<false>(B0, xt, tid, ty0, tx0);
        conv_gate(B1, wfh[1], acc16, col, q8);
        __syncthreads();

        // cix0 (x ch 0-31, global weights) | stage x ch 32-63
        {
            bf16x8 wfx[9];
            #pragma unroll
            for (int tap = 0; tap < 9; ++tap)
                wfx[tap] = *(const bf16x8*)(wq + (size_t)tap * 2048
                                            + w * 512 + lane * 8);
            stage_chunk<false>(B1, xt + 32, tid, ty0, tx0);
            conv_gate(B0, wfx, acc16, col, q8);
        }
        __syncthreads();

        // cix1 (x ch 32-63, global weights)
        {
            bf16x8 wfx[9];
            #pragma unroll
            for (int tap = 0; tap < 9; ++tap)
                wfx[tap] = *(const bf16x8*)(wq + (size_t)73728
                                            + tap * 2048 + w * 512 + lane * 8);
            conv_gate(B1, wfx, acc16, col, q8);
        }

        // ---- epilogue: gate exchange via LDS (2 halves of 8 rows) ----
        float* ex = (float*)zs;   // 32 KB: [gate][row-in-half][px][hc] f32
        #pragma unroll
        for (int hh = 0; hh < 2; ++hh) {
            __syncthreads();      // zs free (cix1 reads done / half0 reads done)
            #pragma unroll
            for (int j = 0; j < 8; ++j)
                #pragma unroll
                for (int reg = 0; reg < 4; ++reg)
                    ex[w * 2048 + j * 256 + (quad * 4 + reg) * 16 + col] =
                        acc16[8 * hh + j][reg];
            __syncthreads();
            #pragma unroll
            for (int k = 0; k < 2; ++k) {
                const int rloc = 2 * w + k;
                const int r16  = 8 * hh + rloc;
                const int cpI  = hh * 2 + k;
                const size_t rowbase =
                    ((size_t)((ty0 + r16) * 64) + gx_) * 64 + hc0 + col;
                #pragma unroll
                for (int reg = 0; reg < 4; ++reg) {
                    const int eb = rloc * 256 + (quad * 4 + reg) * 16 + col;
                    const float ci  = ex[eb];
                    const float cf  = ex[2048 + eb];
                    const float co  = ex[4096 + eb];
                    const float cgv = ex[6144 + eb];
                    const float cn  = sigf(cf) * cpv[cpI][reg] + sigf(ci) * tanhf(cgv);
                    const float hn  = sigf(co) * tanhf(cn);
                    cpv[cpI][reg] = cn;
                    const ushort hb = f2bf(hn);
                    if (fast)
                        ho[rowbase + (size_t)reg * 64] = hb;
                    else
                        __hip_atomic_store(&ho[rowbase + (size_t)reg * 64], hb,
                                           __ATOMIC_RELAXED, __HIP_MEMORY_SCOPE_AGENT);
                    if (t == 15)
                        cb[rowbase + (size_t)reg * 64] = cn;
                }
            }
        }

        if (t < 15) {
            // ---- per-batch grid barrier (r14) ----
            __syncthreads();      // drain h stores (vmcnt 0) before arrive
            if (tid == 0) {
                unsigned* c = &bar[(t * 8 + b) * 16];
                __hip_atomic_fetch_add(c, 1u, __ATOMIC_RELAXED,
                                       __HIP_MEMORY_SCOPE_AGENT);
                while (__hip_atomic_load(c, __ATOMIC_RELAXED,
                                         __HIP_MEMORY_SCOPE_AGENT) < BBLK)
                    __builtin_amdgcn_s_sleep(16);
            }
            __syncthreads();
        }
    }
}

// NHWC -> NCHW final outputs: d_out = [h fp32 | c fp32], each (8,64,4096)
__global__ __launch_bounds__(256) void conv_out(
    const ushort* __restrict__ hN, const float* __restrict__ cN,
    float* __restrict__ out)
{
    __shared__ float T[64][65];
    const int tid  = threadIdx.x;
    const int pg   = blockIdx.x;        // 64 pixel-groups of 64
    const int b    = blockIdx.y;
    const int tsel = blockIdx.z;        // 0 = h, 1 = c
    const int pix0 = pg * 64;

    #pragma unroll
    for (int k = 0; k < 16; ++k) {
        const int idx = k * 256 + tid;
        const int pl = idx >> 6, ch = idx & 63;
        const size_t src = (size_t)b * CHW + (size_t)(pix0 + pl) * 64 + ch;
        T[pl][ch] = tsel ? cN[src] : bf2f(hN[src]);
    }
    __syncthreads();
    float* base = out + (tsel ? 2097152 : 0);
    #pragma unroll
    for (int k = 0; k < 16; ++k) {
        const int idx = k * 256 + tid;
        const int ch = idx >> 6, pl = idx & 63;
        base[(size_t)b * CHW + (size_t)ch * 4096 + pix0 + pl] = T[pl][ch];
    }
}

extern "C" void kernel_launch(void* const* d_in, const int* in_sizes, int n_in,
                              void* d_out, int out_size, void* d_ws, size_t ws_size,
                              hipStream_t stream) {
    const float* x  = (const float*)d_in[0];
    const float* Wk = (const float*)d_in[1];
    float* out = (float*)d_out;

    char* ws = (char*)d_ws;
    ushort*   Wt  = (ushort*)ws;                       // 589,824 B @ 0
    unsigned* bar = (unsigned*)(ws + 917504);          // 16,384 B @ 896 KB
    float*    cb  = (float*)(ws + (1u << 20));         // 8,388,608 B @ 1 MB
    ushort*   hb0 = (ushort*)(ws + (16u << 20));       // 4,194,304 B @ 16 MB
    ushort*   hb1 = (ushort*)(ws + (20u << 20));       // 4,194,304 B @ 20 MB
    ushort*   xb  = (ushort*)(ws + (32u << 20));       // 67,108,864 B @ 32 MB

    (void)hipMemsetAsync(hb0, 0, 4194304, stream);     // h(-1) = 0
    (void)hipMemsetAsync(bar, 0, 16384, stream);       // counters + masks
    transform_w<<<144, 256, 0, stream>>>(Wk, Wt);
    xconv<<<dim3(16, 128), 256, 0, stream>>>(x, xb);

    convlstm_all<<<512, 256, 0, stream>>>(xb, Wt, hb0, hb1, cb, bar);

    // t=15 wrote hb0
    conv_out<<<dim3(64, 8, 2), 256, 0, stream>>>(hb0, cb, out);
}